// Round 3
// baseline (134.865 us; speedup 1.0000x reference)
//
#include <hip/hip_runtime.h>

// Problem constants (from reference)
#define B_    16
#define N_    8192
#define FEAT_ 256
#define MEM_  128
#define U_    512

#define NCHUNK 64
#define ROWS_PER_CHUNK (N_ / NCHUNK)   // 128 rows per block

// ---------------------------------------------------------------------------
// Exact algebraic reduction of the reference:
//   softmax over u followed by mean over the SAME u axis => attn rows sum to 1
//   out[b,m] = (1/U) sum_n V[b,n,m];  V = X@Wv + bv
//   => S[b,f] = sum_n X[b,n,f];  out0 = (S@Wv + N*bv)/U;  out = relu(out0@Wo+bo)
// K, mem, Wk, bk, scores, softmax are all mathematically dead.
//
// Single fused kernel, last-block-per-batch finish (threadFenceReduction
// pattern). cnt[] zeroed by a hipMemsetAsync node each call (d_ws is poisoned
// 0xAA once before timing and never re-poisoned).
// ---------------------------------------------------------------------------

#define PART_FLOATS (B_ * NCHUNK * FEAT_)   // 1 MiB of f32 partials in d_ws

__global__ __launch_bounds__(256) void fused_memblock(
    const float* __restrict__ X,
    const float* __restrict__ Wv, const float* __restrict__ bv,
    const float* __restrict__ Wo, const float* __restrict__ bo,
    float* __restrict__ part, unsigned* __restrict__ cnt,
    float* __restrict__ out) {

    const int bid   = blockIdx.x;
    const int chunk = bid & (NCHUNK - 1);
    const int b     = bid >> 6;
    const int tid   = threadIdx.x;
    const int f4    = tid & 63;   // which float4 of the 256-feature row
    const int phase = tid >> 6;   // 0..3

    __shared__ float  sW[64 * MEM_];   // 32 KB weight tile (Wv/Wo staging)
    __shared__ float4 sacc[256];       // 4 KB combine buffer
    __shared__ float  sX[FEAT_];       // summed S row
    __shared__ float  sO[MEM_];        // out0 row
    __shared__ float  sH[2][MEM_];     // half-dot partials
    __shared__ int    sLast;

    // ---- phase 1: column-sum of this chunk's 128 rows (coalesced 1KB/wave)
    {
        const float4* Xrow = (const float4*)(X + (size_t)b * N_ * FEAT_);
        float4 acc = make_float4(0.f, 0.f, 0.f, 0.f);
        const int n0 = chunk * ROWS_PER_CHUNK;
        #pragma unroll 4
        for (int n = n0 + phase; n < n0 + ROWS_PER_CHUNK; n += 4) {
            float4 v = Xrow[(size_t)n * (FEAT_ / 4) + f4];
            acc.x += v.x; acc.y += v.y; acc.z += v.z; acc.w += v.w;
        }
        sacc[tid] = acc;
    }
    __syncthreads();
    if (phase == 0) {
        float4 a = sacc[f4], b1 = sacc[64 + f4], c = sacc[128 + f4], d = sacc[192 + f4];
        float4 t;
        t.x = (a.x + b1.x) + (c.x + d.x);
        t.y = (a.y + b1.y) + (c.y + d.y);
        t.z = (a.z + b1.z) + (c.z + d.z);
        t.w = (a.w + b1.w) + (c.w + d.w);
        ((float4*)part)[((size_t)b * NCHUNK + chunk) * (FEAT_ / 4) + f4] = t;
    }

    // ---- release + arrive
    __threadfence();                 // make part writes device-visible
    __syncthreads();
    if (tid == 0) {
        unsigned old = atomicAdd(&cnt[b], 1u);
        sLast = (old == NCHUNK - 1);
    }
    __syncthreads();
    if (!sLast) return;

    // ---- this block is the last of batch b: do the finish for batch b
    __threadfence();                 // acquire: invalidate stale cache lines

    // S-reduce: sum the 64 chunk partials (fixed order -> deterministic)
    {
        const float4* p4 = (const float4*)(part + (size_t)b * NCHUNK * FEAT_);
        float4 pr = make_float4(0.f, 0.f, 0.f, 0.f);
        #pragma unroll 4
        for (int c = phase; c < NCHUNK; c += 4) {
            float4 v = p4[c * (FEAT_ / 4) + f4];
            pr.x += v.x; pr.y += v.y; pr.z += v.z; pr.w += v.w;
        }
        sacc[tid] = pr;
    }
    __syncthreads();
    if (tid < 64) {
        float4 a = sacc[tid], b2 = sacc[64 + tid], c2 = sacc[128 + tid], d2 = sacc[192 + tid];
        float4 t;
        t.x = (a.x + b2.x) + (c2.x + d2.x);
        t.y = (a.y + b2.y) + (c2.y + d2.y);
        t.z = (a.z + b2.z) + (c2.z + d2.z);
        t.w = (a.w + b2.w) + (c2.w + d2.w);
        ((float4*)sX)[tid] = t;
    }
    __syncthreads();

    const int m = tid & 127;
    const int h = tid >> 7;          // 2-way split of the reduction axis

    // matvec1: out0[m] = (sum_f S[f]*Wv[f][m] + N*bv[m]) / U, Wv in 4 LDS tiles
    float accm = 0.f;
    for (int t = 0; t < 4; ++t) {
        const float4* wv4 = ((const float4*)Wv) + t * (64 * MEM_ / 4);
        float4* sW4 = (float4*)sW;
        #pragma unroll
        for (int i = 0; i < (64 * MEM_ / 4) / 256; ++i)      // 8 iters
            sW4[tid + i * 256] = wv4[tid + i * 256];
        __syncthreads();
        const int fbase = t * 64 + h * 32;
        #pragma unroll 8
        for (int r = 0; r < 32; ++r)
            accm = fmaf(sX[fbase + r], sW[(h * 32 + r) * MEM_ + m], accm);
        __syncthreads();
    }
    sH[h][m] = accm;
    __syncthreads();
    if (tid < MEM_)
        sO[tid] = (sH[0][tid] + sH[1][tid] + (float)N_ * bv[tid]) * (1.0f / (float)U_);
    __syncthreads();

    // matvec2 + relu: Wo in 2 LDS tiles
    float acc2 = 0.f;
    for (int t = 0; t < 2; ++t) {
        const float4* wo4 = ((const float4*)Wo) + t * (64 * MEM_ / 4);
        float4* sW4 = (float4*)sW;
        #pragma unroll
        for (int i = 0; i < (64 * MEM_ / 4) / 256; ++i)      // 8 iters
            sW4[tid + i * 256] = wo4[tid + i * 256];
        __syncthreads();
        const int kbase = t * 64 + h * 32;
        #pragma unroll 8
        for (int r = 0; r < 32; ++r)
            acc2 = fmaf(sO[kbase + r], sW[(h * 32 + r) * MEM_ + m], acc2);
        __syncthreads();
    }
    sH[h][m] = acc2;
    __syncthreads();
    if (tid < MEM_)
        out[b * MEM_ + tid] = fmaxf(sH[0][tid] + sH[1][tid] + bo[tid], 0.f);
}

// ---------------------------------------------------------------------------
extern "C" void kernel_launch(void* const* d_in, const int* in_sizes, int n_in,
                              void* d_out, int out_size, void* d_ws, size_t ws_size,
                              hipStream_t stream) {
    const float* X  = (const float*)d_in[0];
    // d_in[1] = mem, d_in[2] = Wk, d_in[3] = bk  -- mathematically dead
    const float* Wv = (const float*)d_in[4];
    const float* bv = (const float*)d_in[5];
    const float* Wo = (const float*)d_in[6];
    const float* bo = (const float*)d_in[7];
    float* out  = (float*)d_out;
    float*    part = (float*)d_ws;
    unsigned* cnt  = (unsigned*)((char*)d_ws + (size_t)PART_FLOATS * 4);

    // Deterministic counter init each call (d_ws poison is 0xAA, not 0).
    hipMemsetAsync(cnt, 0, B_ * sizeof(unsigned), stream);

    fused_memblock<<<dim3(B_ * NCHUNK), 256, 0, stream>>>(
        X, Wv, bv, Wo, bo, part, cnt, out);
}

// Round 4
// 32.955 us; speedup vs baseline: 4.0924x; 4.0924x over previous
//
#include <hip/hip_runtime.h>

// Problem constants (from reference)
#define B_    16
#define N_    8192
#define FEAT_ 256
#define MEM_  128
#define U_    512

// ---------------------------------------------------------------------------
// Exact algebraic reduction of the reference:
//   softmax over u followed by mean over the SAME u axis => attn rows sum to 1
//   out[b,m] = (1/U) sum_n V[b,n,m];  V = X@Wv + bv
//   => S[b,f] = sum_n X[b,n,f];  out0 = (S@Wv + N*bv)/U;  out = relu(out0@Wo+bo)
// K, mem, Wk, bk, scores, softmax are all mathematically dead.
//
// Two kernels (round-3 lesson: per-block device fences = serialized L2
// writebacks = 4x regression; stay with plain kernel boundary for the
// cross-block dependency).
// ---------------------------------------------------------------------------

// Kernel 1: partial column sums of X over N.
//   part layout: [B][CHUNKS][FEAT]
//   grid (CHUNKS, B), 256 threads. Wave = one full 1KB row read (coalesced).
//   Fully unrolled independent loads (N_/CHUNKS/4 per thread) for MLP.
template <int CHUNKS>
__global__ __launch_bounds__(256) void colsum_partial(
    const float* __restrict__ X, float* __restrict__ part) {
    constexpr int ROWS  = N_ / CHUNKS;      // rows per block
    constexpr int LOADS = ROWS / 4;         // float4 loads per thread

    const int chunk = blockIdx.x;
    const int b     = blockIdx.y;
    const int tid   = threadIdx.x;
    const int f4    = tid & 63;   // which float4 of the 256-feature row
    const int phase = tid >> 6;   // 0..3 row phase

    const float4* Xrow = (const float4*)(X + (size_t)b * N_ * FEAT_);
    const size_t base = (size_t)(chunk * ROWS + phase) * (FEAT_ / 4) + f4;

    float4 a0 = make_float4(0.f, 0.f, 0.f, 0.f);
    float4 a1 = a0, a2 = a0, a3 = a0;
    #pragma unroll
    for (int i = 0; i < LOADS; i += 4) {
        float4 v0 = Xrow[base + (size_t)(4 * (i + 0)) * (FEAT_ / 4)];
        float4 v1 = Xrow[base + (size_t)(4 * (i + 1)) * (FEAT_ / 4)];
        float4 v2 = Xrow[base + (size_t)(4 * (i + 2)) * (FEAT_ / 4)];
        float4 v3 = Xrow[base + (size_t)(4 * (i + 3)) * (FEAT_ / 4)];
        a0.x += v0.x; a0.y += v0.y; a0.z += v0.z; a0.w += v0.w;
        a1.x += v1.x; a1.y += v1.y; a1.z += v1.z; a1.w += v1.w;
        a2.x += v2.x; a2.y += v2.y; a2.z += v2.z; a2.w += v2.w;
        a3.x += v3.x; a3.y += v3.y; a3.z += v3.z; a3.w += v3.w;
    }
    float4 acc;
    acc.x = (a0.x + a1.x) + (a2.x + a3.x);
    acc.y = (a0.y + a1.y) + (a2.y + a3.y);
    acc.z = (a0.z + a1.z) + (a2.z + a3.z);
    acc.w = (a0.w + a1.w) + (a2.w + a3.w);

    __shared__ float4 sacc[256];
    sacc[tid] = acc;
    __syncthreads();

    if (phase == 0) {
        float4 a = sacc[f4], b1 = sacc[64 + f4], c = sacc[128 + f4], d = sacc[192 + f4];
        float4 t;
        t.x = (a.x + b1.x) + (c.x + d.x);
        t.y = (a.y + b1.y) + (c.y + d.y);
        t.z = (a.z + b1.z) + (c.z + d.z);
        t.w = (a.w + b1.w) + (c.w + d.w);
        ((float4*)part)[((size_t)b * CHUNKS + chunk) * (FEAT_ / 4) + f4] = t;
    }
}

// ---------------------------------------------------------------------------
// Kernel 2: finish. One block per batch, 256 threads.
// Weights staged to LDS (coalesced, independent loads) so the dependent FMA
// chains run at LDS latency. Fixed-order reductions -> deterministic.
// ---------------------------------------------------------------------------
template <int CHUNKS>
__global__ __launch_bounds__(256) void finish_kernel(
    const float* __restrict__ part,
    const float* __restrict__ Wv, const float* __restrict__ bv,
    const float* __restrict__ Wo, const float* __restrict__ bo,
    float* __restrict__ out) {
    const int b   = blockIdx.x;
    const int tid = threadIdx.x;

    __shared__ float  sW[FEAT_ * MEM_];   // 128 KB, reused for Wo (64 KB)
    __shared__ float4 sP4[4][FEAT_ / 4];  // 4 KB chunk partials
    __shared__ float  sX[FEAT_];          // 1 KB
    __shared__ float  sO[MEM_];           // 512 B
    __shared__ float  sH[2][MEM_];        // 1 KB half-dot partials

    // --- A) stage Wv -> LDS (coalesced float4, 32 independent loads/thread)
    {
        const float4* wv4 = (const float4*)Wv;
        float4* sW4 = (float4*)sW;
        #pragma unroll
        for (int i = 0; i < (FEAT_ * MEM_ / 4) / 256; ++i)   // 32 iters
            sW4[tid + i * 256] = wv4[tid + i * 256];
    }

    // --- B) chunk-reduce S: 4-way split over chunks, float4 over features
    {
        const float4* p4 = (const float4*)(part + (size_t)b * CHUNKS * FEAT_);
        const int f4 = tid & 63;
        const int q  = tid >> 6;
        float4 pr = make_float4(0.f, 0.f, 0.f, 0.f);
        #pragma unroll 8
        for (int c = q; c < CHUNKS; c += 4) {
            float4 v = p4[c * (FEAT_ / 4) + f4];
            pr.x += v.x; pr.y += v.y; pr.z += v.z; pr.w += v.w;
        }
        sP4[q][f4] = pr;
    }
    __syncthreads();   // covers Wv staging + partials

    if (tid < 64) {
        float4 a = sP4[0][tid], b2 = sP4[1][tid], c2 = sP4[2][tid], d2 = sP4[3][tid];
        float4 t;
        t.x = (a.x + b2.x) + (c2.x + d2.x);
        t.y = (a.y + b2.y) + (c2.y + d2.y);
        t.z = (a.z + b2.z) + (c2.z + d2.z);
        t.w = (a.w + b2.w) + (c2.w + d2.w);
        ((float4*)sX)[tid] = t;
    }
    __syncthreads();

    // --- C) matvec1: out0[m] = (sum_f S[f]*Wv[f][m] + N*bv[m]) / U
    const int m = tid & 127;
    const int h = tid >> 7;   // 2-way split of the f range
    {
        float acc = 0.f;
        const int f0 = h * (FEAT_ / 2);
        #pragma unroll 8
        for (int f = f0; f < f0 + FEAT_ / 2; ++f)
            acc = fmaf(sX[f], sW[f * MEM_ + m], acc);
        sH[h][m] = acc;
    }
    __syncthreads();   // sW reads complete beyond this point

    // --- D) stage Wo -> LDS (reuse sW) while tid<128 computes sO
    {
        const float4* wo4 = (const float4*)Wo;
        float4* sW4 = (float4*)sW;
        #pragma unroll
        for (int i = 0; i < (MEM_ * MEM_ / 4) / 256; ++i)    // 16 iters
            sW4[tid + i * 256] = wo4[tid + i * 256];
    }
    if (tid < MEM_)
        sO[tid] = (sH[0][tid] + sH[1][tid] + (float)N_ * bv[tid]) * (1.0f / (float)U_);
    __syncthreads();

    // --- E) matvec2 + relu: out[m2] = relu(sum_m sO[m]*Wo[m][m2] + bo[m2])
    {
        float acc = 0.f;
        const int k0 = h * (MEM_ / 2);
        #pragma unroll 8
        for (int k = k0; k < k0 + MEM_ / 2; ++k)
            acc = fmaf(sO[k], sW[k * MEM_ + m], acc);
        sH[h][m] = acc;
    }
    __syncthreads();

    if (tid < MEM_)
        out[b * MEM_ + tid] = fmaxf(sH[0][tid] + sH[1][tid] + bo[tid], 0.f);
}

// ---------------------------------------------------------------------------
extern "C" void kernel_launch(void* const* d_in, const int* in_sizes, int n_in,
                              void* d_out, int out_size, void* d_ws, size_t ws_size,
                              hipStream_t stream) {
    const float* X  = (const float*)d_in[0];
    // d_in[1] = mem, d_in[2] = Wk, d_in[3] = bk  -- mathematically dead
    const float* Wv = (const float*)d_in[4];
    const float* bv = (const float*)d_in[5];
    const float* Wo = (const float*)d_in[6];
    const float* bo = (const float*)d_in[7];
    float* out  = (float*)d_out;
    float* part = (float*)d_ws;

    // 128 chunks -> 2048 blocks (8/CU) needs 2 MiB of scratch; fall back to
    // 64 chunks (1 MiB) if the workspace is small. ws_size is fixed per
    // problem, so the choice is deterministic.
    if (ws_size >= (size_t)B_ * 128 * FEAT_ * sizeof(float)) {
        colsum_partial<128><<<dim3(128, B_), 256, 0, stream>>>(X, part);
        finish_kernel<128><<<B_, 256, 0, stream>>>(part, Wv, bv, Wo, bo, out);
    } else {
        colsum_partial<64><<<dim3(64, B_), 256, 0, stream>>>(X, part);
        finish_kernel<64><<<B_, 256, 0, stream>>>(part, Wv, bv, Wo, bo, out);
    }
}

// Round 5
// 29.291 us; speedup vs baseline: 4.6043x; 1.1251x over previous
//
#include <hip/hip_runtime.h>

// Problem constants (from reference)
#define B_    16
#define N_    8192
#define FEAT_ 256
#define MEM_  128
#define U_    512

#define CHUNKS 64
#define ROWS   (N_ / CHUNKS)     // 128 rows per colsum block
#define NWF    64                // Wf-stripe blocks (4 f-rows each)
#define EXTRA  (NWF + 1)         // + 1 bf block

// ---------------------------------------------------------------------------
// Exact algebraic reduction of the reference:
//   softmax over u then mean over the SAME u axis => attn rows sum to 1
//   out[b,:] = relu( ((S_b @ Wv + N*bv)/U) @ Wo + bo ),  S_b[f] = sum_n X[b,n,f]
// Further fused:  Wf = (Wv@Wo)/U  [256x128],  bf = (N/U)*(bv@Wo) + bo
//   out[b,:] = relu( S_b @ Wf + bf )
// K, mem, Wk, bk, scores, softmax are all mathematically dead.
//
// k1: blocks [0,64] compute WfT/bf (weight-only, hidden under the X stream);
//     blocks [65, 65+1024) do the X column-sum partials.
// k2: 128 small blocks finish (reduce partials + one fused matvec + relu).
// No atomics / device fences (round-3 lesson: per-block fences serialize L2
// writebacks, 4x regression). Fixed-order sums -> deterministic.
// ---------------------------------------------------------------------------

__global__ __launch_bounds__(256) void fused_k1(
    const float* __restrict__ X,
    const float* __restrict__ Wv, const float* __restrict__ bv,
    const float* __restrict__ Wo, const float* __restrict__ bo,
    float* __restrict__ part,     // [B][CHUNKS][FEAT]
    float* __restrict__ WfT,      // [MEM][FEAT] transposed fused weight
    float* __restrict__ bf) {     // [MEM]
    const int bid = blockIdx.x;
    const int tid = threadIdx.x;

    __shared__ float4 sacc[256];        // colsum combine (4 KB)
    __shared__ float  sWv[4 * MEM_];    // 4 Wv rows, [j][k] (2 KB)
    __shared__ float  sB[2][MEM_];      // bf combine (1 KB)

    if (bid < NWF) {
        // ---- WfT[m][4*bid + j] = (1/U) * sum_k Wv[4*bid+j][k] * Wo[k][m]
        const float* src = Wv + (size_t)(4 * bid) * MEM_;   // 512 floats
        sWv[tid]       = src[tid];
        sWv[tid + 256] = src[tid + 256];
        __syncthreads();

        const int m = tid & 127;
        const int h = tid >> 7;          // f-pair selector: f = 4*bid + 2h {+1}
        const float* wvr0 = &sWv[(2 * h) * MEM_];
        const float* wvr1 = &sWv[(2 * h + 1) * MEM_];
        float a0 = 0.f, a1 = 0.f;
        #pragma unroll 8
        for (int k = 0; k < MEM_; ++k) {
            float w = Wo[k * MEM_ + m];  // coalesced across the 128 m-threads
            a0 = fmaf(wvr0[k], w, a0);
            a1 = fmaf(wvr1[k], w, a1);
        }
        float* dst = WfT + (size_t)m * FEAT_ + 4 * bid + 2 * h;
        dst[0] = a0 * (1.0f / (float)U_);
        dst[1] = a1 * (1.0f / (float)U_);
    } else if (bid == NWF) {
        // ---- bf[m] = (N/U) * sum_k bv[k]*Wo[k][m] + bo[m]
        const int m = tid & 127;
        const int h = tid >> 7;
        float a = 0.f;
        #pragma unroll 8
        for (int k = h * 64; k < h * 64 + 64; ++k)
            a = fmaf(bv[k], Wo[k * MEM_ + m], a);
        sB[h][m] = a;
        __syncthreads();
        if (tid < MEM_)
            bf[tid] = ((float)N_ / (float)U_) * (sB[0][tid] + sB[1][tid]) + bo[tid];
    } else {
        // ---- column-sum partial of one 128-row chunk (coalesced 1KB/wave)
        const int cid   = bid - EXTRA;
        const int chunk = cid & (CHUNKS - 1);
        const int b     = cid >> 6;
        const int f4    = tid & 63;   // which float4 of the 256-feature row
        const int phase = tid >> 6;   // 0..3 row phase

        const float4* Xrow = (const float4*)(X + (size_t)b * N_ * FEAT_);
        const size_t base = (size_t)(chunk * ROWS + phase) * (FEAT_ / 4) + f4;

        float4 a0 = make_float4(0.f, 0.f, 0.f, 0.f);
        float4 a1 = a0, a2 = a0, a3 = a0;
        #pragma unroll
        for (int i = 0; i < ROWS / 4; i += 4) {   // 32 loads, 4 accum chains
            float4 v0 = Xrow[base + (size_t)(4 * (i + 0)) * (FEAT_ / 4)];
            float4 v1 = Xrow[base + (size_t)(4 * (i + 1)) * (FEAT_ / 4)];
            float4 v2 = Xrow[base + (size_t)(4 * (i + 2)) * (FEAT_ / 4)];
            float4 v3 = Xrow[base + (size_t)(4 * (i + 3)) * (FEAT_ / 4)];
            a0.x += v0.x; a0.y += v0.y; a0.z += v0.z; a0.w += v0.w;
            a1.x += v1.x; a1.y += v1.y; a1.z += v1.z; a1.w += v1.w;
            a2.x += v2.x; a2.y += v2.y; a2.z += v2.z; a2.w += v2.w;
            a3.x += v3.x; a3.y += v3.y; a3.z += v3.z; a3.w += v3.w;
        }
        float4 acc;
        acc.x = (a0.x + a1.x) + (a2.x + a3.x);
        acc.y = (a0.y + a1.y) + (a2.y + a3.y);
        acc.z = (a0.z + a1.z) + (a2.z + a3.z);
        acc.w = (a0.w + a1.w) + (a2.w + a3.w);

        sacc[tid] = acc;
        __syncthreads();

        if (phase == 0) {
            float4 a = sacc[f4], b1 = sacc[64 + f4], c = sacc[128 + f4], d = sacc[192 + f4];
            float4 t;
            t.x = (a.x + b1.x) + (c.x + d.x);
            t.y = (a.y + b1.y) + (c.y + d.y);
            t.z = (a.z + b1.z) + (c.z + d.z);
            t.w = (a.w + b1.w) + (c.w + d.w);
            ((float4*)part)[((size_t)b * CHUNKS + chunk) * (FEAT_ / 4) + f4] = t;
        }
    }
}

// ---------------------------------------------------------------------------
// k2: 128 blocks = (batch b, m-group of 16). Reduce partials to S (coalesced,
// fixed order), then each thread does one 16-wide segment of a fused dot,
// LDS-combine 16 segments, add bf, relu, store.
// ---------------------------------------------------------------------------
__global__ __launch_bounds__(256) void finish_k2(
    const float* __restrict__ part, const float* __restrict__ WfT,
    const float* __restrict__ bf, float* __restrict__ out) {
    const int mg  = blockIdx.x & 7;
    const int b   = blockIdx.x >> 3;
    const int tid = threadIdx.x;

    __shared__ float sX[FEAT_];
    __shared__ float sRed[16][17];   // +1 pad

    // step 1: S[f] = sum_c part[b][c][f]  (64 coalesced loads, 4 chains)
    {
        const float* p = part + (size_t)b * CHUNKS * FEAT_ + tid;
        float s0 = 0.f, s1 = 0.f, s2 = 0.f, s3 = 0.f;
        #pragma unroll
        for (int c = 0; c < CHUNKS; c += 4) {
            s0 += p[(c + 0) * FEAT_];
            s1 += p[(c + 1) * FEAT_];
            s2 += p[(c + 2) * FEAT_];
            s3 += p[(c + 3) * FEAT_];
        }
        sX[tid] = (s0 + s1) + (s2 + s3);
    }
    __syncthreads();

    // step 2: 16-wide segment dots against WfT row m
    const int mi = tid & 15;
    const int ki = tid >> 4;
    const int m  = mg * 16 + mi;
    {
        const float4* wrow = (const float4*)(WfT + (size_t)m * FEAT_ + ki * 16);
        const float4* xseg = (const float4*)(&sX[ki * 16]);
        float acc = 0.f;
        #pragma unroll
        for (int j = 0; j < 4; ++j) {
            float4 w = wrow[j];
            float4 x = xseg[j];
            acc += (w.x * x.x + w.y * x.y) + (w.z * x.z + w.w * x.w);
        }
        sRed[mi][ki] = acc;
    }
    __syncthreads();

    // step 3: combine 16 segments (fixed order), bias, relu, store
    if (tid < 16) {
        float a = 0.f;
        #pragma unroll
        for (int k = 0; k < 16; ++k)
            a += sRed[tid][k];
        const int mm = mg * 16 + tid;
        out[b * MEM_ + mm] = fmaxf(a + bf[mm], 0.f);
    }
}

// ---------------------------------------------------------------------------
extern "C" void kernel_launch(void* const* d_in, const int* in_sizes, int n_in,
                              void* d_out, int out_size, void* d_ws, size_t ws_size,
                              hipStream_t stream) {
    const float* X  = (const float*)d_in[0];
    // d_in[1] = mem, d_in[2] = Wk, d_in[3] = bk  -- mathematically dead
    const float* Wv = (const float*)d_in[4];
    const float* bv = (const float*)d_in[5];
    const float* Wo = (const float*)d_in[6];
    const float* bo = (const float*)d_in[7];
    float* out  = (float*)d_out;

    float* part = (float*)d_ws;                       // 1 MiB
    float* WfT  = part + (size_t)B_ * CHUNKS * FEAT_; // 128 KiB
    float* bf   = WfT + (size_t)MEM_ * FEAT_;         // 512 B

    fused_k1<<<dim3(EXTRA + CHUNKS * B_), 256, 0, stream>>>(
        X, Wv, bv, Wo, bo, part, WfT, bf);
    finish_k2<<<dim3(B_ * 8), 256, 0, stream>>>(part, WfT, bf, out);
}